// Round 20
// baseline (103.840 us; speedup 1.0000x reference)
//
#include <hip/hip_runtime.h>

#define BTOT 65536
#define TST  28
#define PACK_DW 180
// ws layout (dwords): [0 .. 11520) packed frags (64 lanes x 180)
//                     [11520 .. 15616) WxL: 32 x 128 f32 (rows 29..31 zeroed)
#define WXL_OFF (64 * PACK_DW)

typedef __attribute__((ext_vector_type(8))) short bf16x8;
typedef __attribute__((ext_vector_type(4))) float f32x4;
typedef __attribute__((ext_vector_type(2))) unsigned int u32x2;

__device__ __forceinline__ unsigned int f2bf(float f) {
    unsigned u = __float_as_uint(f);
    u += 0x7fff + ((u >> 16) & 1);   // RNE
    return u >> 16;
}
__device__ __forceinline__ unsigned int pk2bf(float a, float b) {
    return f2bf(a) | (f2bf(b) << 16);
}
__device__ __forceinline__ bf16x8 cvt8(f32x4 a, f32x4 b) {
    union { unsigned int u[4]; bf16x8 v; } r;
    asm("v_cvt_pk_bf16_f32 %0, %1, %2" : "=v"(r.u[0]) : "v"(a[0]), "v"(a[1]));
    asm("v_cvt_pk_bf16_f32 %0, %1, %2" : "=v"(r.u[1]) : "v"(a[2]), "v"(a[3]));
    asm("v_cvt_pk_bf16_f32 %0, %1, %2" : "=v"(r.u[2]) : "v"(b[0]), "v"(b[1]));
    asm("v_cvt_pk_bf16_f32 %0, %1, %2" : "=v"(r.u[3]) : "v"(b[2]), "v"(b[3]));
    return r.v;
}

// pack1: blocks 0..28 compute WxL row k (Wx = W1@W2a; row 28 = b2 + b1@W2a, hit
// by x-frag element k=28 := 1.0; block 28 zeroes rows 29..31). Block 29 packs
// W2b A-frags; block 30 packs W3 frags + b3 D-init.
// Per-lane dword layout: [0..128) w2b(kk,t8) | [128..160) wx(t8)
//                        [160..176) w3(kk)   | [176..180) b3 (f32, D rows)
__global__ void pack1(const float* __restrict__ W1, const float* __restrict__ b1,
                      const float* __restrict__ W2, const float* __restrict__ b2,
                      const float* __restrict__ W3, const float* __restrict__ b3,
                      unsigned int* __restrict__ ws) {
    float* WxL = (float*)(ws + WXL_OFF);
    const int bid = blockIdx.x, tid = threadIdx.x;
    if (bid < 29) {
        const int k = bid, n = tid;   // 128 threads
        float s = 0.f;
        if (k < 28) {
            for (int m = 0; m < 128; ++m) s += W1[k * 128 + m] * W2[m * 128 + n];
        } else {
            s = b2[n];
            for (int m = 0; m < 128; ++m) s += b1[m] * W2[m * 128 + n];
        }
        WxL[k * 128 + n] = s;
        if (k == 28) { WxL[29*128+n] = 0.f; WxL[30*128+n] = 0.f; WxL[31*128+n] = 0.f; }
    } else if (bid == 29) {
        if (tid < 64) {
            const int lr = tid & 15, kh = tid >> 4;
            unsigned int* P = ws + tid * PACK_DW;
            for (int kk = 0; kk < 4; ++kk)
                for (int t8 = 0; t8 < 8; ++t8)
                    for (int jd = 0; jd < 4; ++jd) {
                        const int k = 128 + kk * 32 + kh * 8 + jd * 2;
                        const int n = t8 * 16 + lr;
                        P[(kk * 8 + t8) * 4 + jd] =
                            pk2bf(W2[k * 128 + n], W2[(k + 1) * 128 + n]);
                    }
        }
    } else {
        if (tid < 64) {
            const int lr = tid & 15, kh = tid >> 4;
            unsigned int* P = ws + tid * PACK_DW;
            for (int kk = 0; kk < 4; ++kk)
                for (int jd = 0; jd < 4; ++jd) {
                    const int k = kk * 32 + kh * 8 + jd * 2;
                    float lo = (lr < 10) ? W3[k * 10 + lr] : 0.f;
                    float hi = (lr < 10) ? W3[(k + 1) * 10 + lr] : 0.f;
                    P[160 + kk * 4 + jd] = pk2bf(lo, hi);
                }
            for (int j = 0; j < 4; ++j) {
                const int o = kh * 4 + j;
                P[176 + j] = __float_as_uint((o < 10) ? b3[o] : 0.f);
            }
        }
    }
}

// pack2: Wx A-frags (needs WxL from pack1's blocks 0..28).
__global__ void pack2(unsigned int* __restrict__ ws) {
    const int tid = threadIdx.x;
    if (tid < 64) {
        const float* WxL = (const float*)(ws + WXL_OFF);
        const int lr = tid & 15, kh = tid >> 4;
        unsigned int* P = ws + tid * PACK_DW;
        for (int t8 = 0; t8 < 8; ++t8)
            for (int jd = 0; jd < 4; ++jd) {
                const int k = kh * 8 + jd * 2, n = t8 * 16 + lr;
                P[128 + t8 * 4 + jd] = pk2bf(WxL[k * 128 + n], WxL[(k + 1) * 128 + n]);
            }
    }
}

#define MFMA(a, b, c) __builtin_amdgcn_mfma_f32_16x16x32_bf16(a, b, c, 0, 0, 0)

// ILP-for-TLP experiment: ONE wave per SIMD (launch_bounds(64,1), ~290 VGPR —
// gfx950 spills only near 512 per m08), carrying TWO independent 16-row batch
// groups. 16 independent acc chains keep the MFMA pipe fed from a single wave;
// group B's cluster overlaps group A's cvt/store tail by dataflow. Barrier-free
// wave-private frag-order H (r17), step-0 h-skip + loop-carried hbv (r19).
__global__ __launch_bounds__(64, 1) void rnn_kernel(
    const float* __restrict__ x, const unsigned int* __restrict__ wsPack,
    float* __restrict__ out)
{
    __shared__ __align__(16) unsigned int Hs[2][1024];   // [group][frag-order]
    const int lane = threadIdx.x;
    const int lr = lane & 15, kh = lane >> 4;
    const int r0 = blockIdx.x * 32;

    const unsigned int* P = wsPack + lane * PACK_DW;
    bf16x8 w2b[4][8], wx[8];
    #pragma unroll
    for (int kk = 0; kk < 4; ++kk)
        #pragma unroll
        for (int t8 = 0; t8 < 8; ++t8)
            w2b[kk][t8] = *(const bf16x8*)(P + (kk * 8 + t8) * 4);
    #pragma unroll
    for (int t8 = 0; t8 < 8; ++t8) wx[t8] = *(const bf16x8*)(P + 128 + t8 * 4);

    // write addresses (dwords): D-tile t8 row kh*4+j, batch lr ->
    // frag kk=t8>>1, reader-lane row 2*(t8&1)+(kh>>1), dword (kh&1)*2
    unsigned wAddr[8];
    #pragma unroll
    for (int t8 = 0; t8 < 8; ++t8)
        wAddr[t8] = (t8 >> 1) * 256 + (2 * (t8 & 1) + (kh >> 1)) * 64
                  + lr * 4 + (kh & 1) * 2;

    // x B-frags: lane (kh,lr) covers k = 8kh + j of x[row][28t + k];
    // kh==3 upper half = {1.0 (k=28 bias hook), 0, 0, 0} — Wx rows 29..31 zero.
    const f32x4 onec = {1.f, 0.f, 0.f, 0.f};
    const float* xrA = x + (size_t)(r0 + lr) * 784 + 8 * kh;
    const float* xrB = xrA + 16 * 784;
    f32x4 qa = *(const f32x4*)xrA;
    f32x4 qc = (kh < 3) ? *(const f32x4*)(xrA + 4) : onec;
    bf16x8 xbA = cvt8(qa, qc);
    qa = *(const f32x4*)xrB;
    qc = (kh < 3) ? *(const f32x4*)(xrB + 4) : onec;
    bf16x8 xbB = cvt8(qa, qc);
    const f32x4 z4 = {0.f, 0.f, 0.f, 0.f};

    f32x4 accA[8], accB[8];
    bf16x8 hbvA[4], hbvB[4];
    f32x4 naA, ncA, naB, ncB;
    unsigned int* HsA = &Hs[0][0];
    unsigned int* HsB = &Hs[1][0];

// relu + pack ACC[T8] -> one b64 store into HSP's frag-order slot
#define ST1(HSP, ACC, T8) do {                                              \
        f32x4 v = ACC[T8];                                                  \
        v[0] = fmaxf(v[0], 0.f); v[1] = fmaxf(v[1], 0.f);                   \
        v[2] = fmaxf(v[2], 0.f); v[3] = fmaxf(v[3], 0.f);                   \
        unsigned lo, hi;                                                    \
        asm("v_cvt_pk_bf16_f32 %0, %1, %2" : "=v"(lo) : "v"(v[0]), "v"(v[1])); \
        asm("v_cvt_pk_bf16_f32 %0, %1, %2" : "=v"(hi) : "v"(v[2]), "v"(v[3])); \
        u32x2 st = {lo, hi};                                                \
        *(u32x2*)&(HSP)[wAddr[T8]] = st;                                    \
    } while (0)
// read HBV[KK]: safe right after stores t8=2KK, 2KK+1 (in-wave LDS in-order)
#define RD1(HSP, HBV, KK) HBV[KK] = *(const bf16x8*)&(HSP)[(KK) * 256 + lane * 4]
#define STRD(HSP, ACC, HBV)                       \
    ST1(HSP, ACC, 0); ST1(HSP, ACC, 1); RD1(HSP, HBV, 0); \
    ST1(HSP, ACC, 2); ST1(HSP, ACC, 3); RD1(HSP, HBV, 1); \
    ST1(HSP, ACC, 4); ST1(HSP, ACC, 5); RD1(HSP, HBV, 2); \
    ST1(HSP, ACC, 6); ST1(HSP, ACC, 7); RD1(HSP, HBV, 3)

    // ---- step 0: h0 == 0, x part only (exact) ----
    {
        const float* xp = xrA + 28;
        naA = *(const f32x4*)xp;
        ncA = (kh < 3) ? *(const f32x4*)(xp + 4) : onec;
        xp = xrB + 28;
        naB = *(const f32x4*)xp;
        ncB = (kh < 3) ? *(const f32x4*)(xp + 4) : onec;
        #pragma unroll
        for (int t8 = 0; t8 < 8; ++t8) {
            accA[t8] = MFMA(wx[t8], xbA, z4);
            accB[t8] = MFMA(wx[t8], xbB, z4);
        }
        STRD(HsA, accA, hbvA);
        STRD(HsB, accB, hbvB);
        xbA = cvt8(naA, ncA);
        xbB = cvt8(naB, ncB);
    }

    // ---- steps 1..27: interleaved dual-group chains ----
    #pragma unroll 2
    for (int t = 1; t < TST; ++t) {
        const bool pf = (t + 1 < TST);
        if (pf) {
            const float* xp = xrA + (t + 1) * 28;
            naA = *(const f32x4*)xp;
            ncA = (kh < 3) ? *(const f32x4*)(xp + 4) : onec;
            xp = xrB + (t + 1) * 28;
            naB = *(const f32x4*)xp;
            ncB = (kh < 3) ? *(const f32x4*)(xp + 4) : onec;
        }
        #pragma unroll
        for (int t8 = 0; t8 < 8; ++t8) {
            accA[t8] = MFMA(wx[t8], xbA, z4);
            accB[t8] = MFMA(wx[t8], xbB, z4);
        }
        #pragma unroll
        for (int kk = 0; kk < 4; ++kk)
            #pragma unroll
            for (int t8 = 0; t8 < 8; ++t8) {
                accA[t8] = MFMA(w2b[kk][t8], hbvA[kk], accA[t8]);
                accB[t8] = MFMA(w2b[kk][t8], hbvB[kk], accB[t8]);
            }
        STRD(HsA, accA, hbvA);   // A tail can sink into B's remaining window
        STRD(HsB, accB, hbvB);
        if (pf) { xbA = cvt8(naA, ncA); xbB = cvt8(naB, ncB); }
    }

    // epilogue: out^T = W3^T . h_final^T + b3 — hbvA/hbvB hold h_final already
    bf16x8 w3f[4];
    #pragma unroll
    for (int kk = 0; kk < 4; ++kk) w3f[kk] = *(const bf16x8*)(P + 160 + kk * 4);
    const float* bp = (const float*)(P + 176);
    f32x4 accO = {bp[0], bp[1], bp[2], bp[3]};
    #pragma unroll
    for (int kk = 0; kk < 4; ++kk)
        accO = MFMA(w3f[kk], hbvA[kk], accO);
    float* op = out + (size_t)(r0 + lr) * 10 + kh * 4;
    #pragma unroll
    for (int j = 0; j < 4; ++j)
        if (kh * 4 + j < 10) op[j] = accO[j];

    accO = (f32x4){bp[0], bp[1], bp[2], bp[3]};
    #pragma unroll
    for (int kk = 0; kk < 4; ++kk)
        accO = MFMA(w3f[kk], hbvB[kk], accO);
    op = out + (size_t)(r0 + 16 + lr) * 10 + kh * 4;
    #pragma unroll
    for (int j = 0; j < 4; ++j)
        if (kh * 4 + j < 10) op[j] = accO[j];

#undef ST1
#undef RD1
#undef STRD
}

extern "C" void kernel_launch(void* const* d_in, const int* in_sizes, int n_in,
                              void* d_out, int out_size, void* d_ws, size_t ws_size,
                              hipStream_t stream) {
    const float* x  = (const float*)d_in[0];
    const float* W1 = (const float*)d_in[1];
    const float* b1 = (const float*)d_in[2];
    const float* W2 = (const float*)d_in[3];
    const float* b2 = (const float*)d_in[4];
    const float* W3 = (const float*)d_in[5];
    const float* b3 = (const float*)d_in[6];
    unsigned int* ws = (unsigned int*)d_ws;   // 15616 dwords = 61 KiB

    pack1<<<31, 128, 0, stream>>>(W1, b1, W2, b2, W3, b3, ws);
    pack2<<<1, 64, 0, stream>>>(ws);
    rnn_kernel<<<BTOT / 32, 64, 0, stream>>>(x, ws, (float*)d_out);
}

// Round 22
// 77.923 us; speedup vs baseline: 1.3326x; 1.3326x over previous
//
#include <hip/hip_runtime.h>

#define BTOT 65536
#define TST  28
#define PACK_DW 180
// ws layout (dwords): [0 .. 11520) packed frags (64 lanes x 180)
//                     [11520 .. 15616) WxL: 32 x 128 f32 (rows 29..31 zeroed)
#define WXL_OFF (64 * PACK_DW)

typedef __attribute__((ext_vector_type(8))) short bf16x8;
typedef __attribute__((ext_vector_type(4))) float f32x4;
typedef __attribute__((ext_vector_type(2))) unsigned int u32x2;

__device__ __forceinline__ unsigned int f2bf(float f) {
    unsigned u = __float_as_uint(f);
    u += 0x7fff + ((u >> 16) & 1);   // RNE
    return u >> 16;
}
__device__ __forceinline__ unsigned int pk2bf(float a, float b) {
    return f2bf(a) | (f2bf(b) << 16);
}
__device__ __forceinline__ bf16x8 cvt8(f32x4 a, f32x4 b) {
    union { unsigned int u[4]; bf16x8 v; } r;
    asm("v_cvt_pk_bf16_f32 %0, %1, %2" : "=v"(r.u[0]) : "v"(a[0]), "v"(a[1]));
    asm("v_cvt_pk_bf16_f32 %0, %1, %2" : "=v"(r.u[1]) : "v"(a[2]), "v"(a[3]));
    asm("v_cvt_pk_bf16_f32 %0, %1, %2" : "=v"(r.u[2]) : "v"(b[0]), "v"(b[1]));
    asm("v_cvt_pk_bf16_f32 %0, %1, %2" : "=v"(r.u[3]) : "v"(b[2]), "v"(b[3]));
    return r.v;
}

// pack1: blocks 0..28 compute WxL row k (Wx = W1@W2a; row 28 = b2 + b1@W2a, hit
// by x-frag element k=28 := 1.0; block 28 zeroes rows 29..31). Block 29 packs
// W2b A-frags; block 30 packs W3 frags + b3 D-init.
// Per-lane dword layout: [0..128) w2b(kk,t8) | [128..160) wx(t8)
//                        [160..176) w3(kk)   | [176..180) b3 (f32, D rows)
__global__ void pack1(const float* __restrict__ W1, const float* __restrict__ b1,
                      const float* __restrict__ W2, const float* __restrict__ b2,
                      const float* __restrict__ W3, const float* __restrict__ b3,
                      unsigned int* __restrict__ ws) {
    float* WxL = (float*)(ws + WXL_OFF);
    const int bid = blockIdx.x, tid = threadIdx.x;
    if (bid < 29) {
        const int k = bid, n = tid;   // 128 threads
        float s = 0.f;
        if (k < 28) {
            for (int m = 0; m < 128; ++m) s += W1[k * 128 + m] * W2[m * 128 + n];
        } else {
            s = b2[n];
            for (int m = 0; m < 128; ++m) s += b1[m] * W2[m * 128 + n];
        }
        WxL[k * 128 + n] = s;
        if (k == 28) { WxL[29*128+n] = 0.f; WxL[30*128+n] = 0.f; WxL[31*128+n] = 0.f; }
    } else if (bid == 29) {
        if (tid < 64) {
            const int lr = tid & 15, kh = tid >> 4;
            unsigned int* P = ws + tid * PACK_DW;
            for (int kk = 0; kk < 4; ++kk)
                for (int t8 = 0; t8 < 8; ++t8)
                    for (int jd = 0; jd < 4; ++jd) {
                        const int k = 128 + kk * 32 + kh * 8 + jd * 2;
                        const int n = t8 * 16 + lr;
                        P[(kk * 8 + t8) * 4 + jd] =
                            pk2bf(W2[k * 128 + n], W2[(k + 1) * 128 + n]);
                    }
        }
    } else {
        if (tid < 64) {
            const int lr = tid & 15, kh = tid >> 4;
            unsigned int* P = ws + tid * PACK_DW;
            for (int kk = 0; kk < 4; ++kk)
                for (int jd = 0; jd < 4; ++jd) {
                    const int k = kk * 32 + kh * 8 + jd * 2;
                    float lo = (lr < 10) ? W3[k * 10 + lr] : 0.f;
                    float hi = (lr < 10) ? W3[(k + 1) * 10 + lr] : 0.f;
                    P[160 + kk * 4 + jd] = pk2bf(lo, hi);
                }
            for (int j = 0; j < 4; ++j) {
                const int o = kh * 4 + j;
                P[176 + j] = __float_as_uint((o < 10) ? b3[o] : 0.f);
            }
        }
    }
}

// pack2: Wx A-frags (needs WxL from pack1's blocks 0..28).
__global__ void pack2(unsigned int* __restrict__ ws) {
    const int tid = threadIdx.x;
    if (tid < 64) {
        const float* WxL = (const float*)(ws + WXL_OFF);
        const int lr = tid & 15, kh = tid >> 4;
        unsigned int* P = ws + tid * PACK_DW;
        for (int t8 = 0; t8 < 8; ++t8)
            for (int jd = 0; jd < 4; ++jd) {
                const int k = kh * 8 + jd * 2, n = t8 * 16 + lr;
                P[128 + t8 * 4 + jd] = pk2bf(WxL[k * 128 + n], WxL[(k + 1) * 128 + n]);
            }
    }
}

// r19 base (77.7us; r17-r19 plateau ~77): 1 wave / 16 rows / all n, zero
// barriers, wave-private frag-order H, step-0 h-skip, loop-carried hbv.
// NEW: anti-convoy stagger keyed on the HARDWARE wave slot (hwreg 4 = HW_ID;
// symbolic name rejected by gfx950 asm parser), not blockIdx parity — the two
// reg-capped co-resident waves per SIMD run identical code in lockstep (both
// MFMA, then both tail -> pipe idles half the time). Odd-slot waves sleep
// ~832cy (half a step) ONCE, anti-phasing the pair so each wave's tail lands
// inside the other's MFMA cluster.
__global__ __launch_bounds__(64, 2) void rnn_kernel(
    const float* __restrict__ x, const unsigned int* __restrict__ wsPack,
    float* __restrict__ out)
{
    __shared__ __align__(16) unsigned int Hs[1024];   // 4 kk-frags x 256 dwords
    const int lane = threadIdx.x;
    const int lr = lane & 15, kh = lane >> 4;
    const int r0 = blockIdx.x * 16;

    const unsigned int* P = wsPack + lane * PACK_DW;
    bf16x8 w2b[4][8], wx[8];
    #pragma unroll
    for (int kk = 0; kk < 4; ++kk)
        #pragma unroll
        for (int t8 = 0; t8 < 8; ++t8)
            w2b[kk][t8] = *(const bf16x8*)(P + (kk * 8 + t8) * 4);
    #pragma unroll
    for (int t8 = 0; t8 < 8; ++t8) wx[t8] = *(const bf16x8*)(P + 128 + t8 * 4);

    // write addresses (dwords): D-tile t8 row kh*4+j, batch lr ->
    // frag kk=t8>>1, reader-lane row 2*(t8&1)+(kh>>1), dword (kh&1)*2
    unsigned wAddr[8];
    #pragma unroll
    for (int t8 = 0; t8 < 8; ++t8)
        wAddr[t8] = (t8 >> 1) * 256 + (2 * (t8 & 1) + (kh >> 1)) * 64
                  + lr * 4 + (kh & 1) * 2;

    // x B-frag: lane (kh,lr) covers k = 8kh + j of x[r0+lr][28t + k];
    // kh==3 upper half = {1.0 (k=28 bias hook), 0, 0, 0} — Wx rows 29..31 zero.
    const f32x4 onec = {1.f, 0.f, 0.f, 0.f};
    const float* xr = x + (size_t)(r0 + lr) * 784 + 8 * kh;
    f32x4 xa = *(const f32x4*)xr;
    f32x4 xc = (kh < 3) ? *(const f32x4*)(xr + 4) : onec;
    bf16x8 xb = cvt8(xa, xc);
    const f32x4 z4 = {0.f, 0.f, 0.f, 0.f};

    // anti-convoy: HW wave slot (wave-uniform) decides the half-step offset.
    // hwreg id 4 = HW_ID on gfx9-lineage; bits [3:0] = wave slot within SIMD.
    {
        unsigned slot;
        asm("s_getreg_b32 %0, hwreg(4, 0, 4)" : "=s"(slot));
        if (slot & 1) __builtin_amdgcn_s_sleep(13);   // ~832 cyc, once
    }

    f32x4 acc[8];
    bf16x8 hbv[4];
    f32x4 na, nc;

// relu + pack acc[T8] -> one b64 store into frag-order slot
#define ST(T8) do {                                                         \
        f32x4 v = acc[T8];                                                  \
        v[0] = fmaxf(v[0], 0.f); v[1] = fmaxf(v[1], 0.f);                   \
        v[2] = fmaxf(v[2], 0.f); v[3] = fmaxf(v[3], 0.f);                   \
        unsigned lo, hi;                                                    \
        asm("v_cvt_pk_bf16_f32 %0, %1, %2" : "=v"(lo) : "v"(v[0]), "v"(v[1])); \
        asm("v_cvt_pk_bf16_f32 %0, %1, %2" : "=v"(hi) : "v"(v[2]), "v"(v[3])); \
        u32x2 st = {lo, hi};                                                \
        *(u32x2*)&Hs[wAddr[T8]] = st;                                       \
    } while (0)
// read hbv[KK]: safe right after stores t8=2KK, 2KK+1 (in-wave LDS in-order)
#define RD(KK) hbv[KK] = *(const bf16x8*)&Hs[(KK) * 256 + lane * 4]
#define STRD  ST(0); ST(1); RD(0); ST(2); ST(3); RD(1); \
              ST(4); ST(5); RD(2); ST(6); ST(7); RD(3)

    // ---- step 0: h0 == 0, so only the x part (exact) ----
    {
        const float* xp = xr + 28;
        na = *(const f32x4*)xp;
        nc = (kh < 3) ? *(const f32x4*)(xp + 4) : onec;
        __builtin_amdgcn_s_setprio(1);
        #pragma unroll
        for (int t8 = 0; t8 < 8; ++t8)
            acc[t8] = __builtin_amdgcn_mfma_f32_16x16x32_bf16(wx[t8], xb, z4, 0, 0, 0);
        __builtin_amdgcn_s_setprio(0);
        xb = cvt8(na, nc);
        STRD;
    }

    // ---- steps 1..27 ----
    #pragma unroll 3
    for (int t = 1; t < TST; ++t) {
        const bool pf = (t + 1 < TST);
        if (pf) {
            const float* xp = xr + (t + 1) * 28;
            na = *(const f32x4*)xp;
            nc = (kh < 3) ? *(const f32x4*)(xp + 4) : onec;
        }
        __builtin_amdgcn_s_setprio(1);
        #pragma unroll
        for (int t8 = 0; t8 < 8; ++t8)
            acc[t8] = __builtin_amdgcn_mfma_f32_16x16x32_bf16(wx[t8], xb, z4, 0, 0, 0);
        #pragma unroll
        for (int kk = 0; kk < 4; ++kk)
            #pragma unroll
            for (int t8 = 0; t8 < 8; ++t8)
                acc[t8] = __builtin_amdgcn_mfma_f32_16x16x32_bf16(w2b[kk][t8], hbv[kk], acc[t8], 0, 0, 0);
        __builtin_amdgcn_s_setprio(0);
        if (pf) xb = cvt8(na, nc);
        STRD;   // stores + next hbv (the last iteration's RDs deliver h_final)
    }

    // epilogue: out^T = W3^T . h_final^T + b3 — hbv already holds h_final
    bf16x8 w3f[4];
    #pragma unroll
    for (int kk = 0; kk < 4; ++kk) w3f[kk] = *(const bf16x8*)(P + 160 + kk * 4);
    const float* bp = (const float*)(P + 176);
    f32x4 accO = {bp[0], bp[1], bp[2], bp[3]};
    #pragma unroll
    for (int kk = 0; kk < 4; ++kk)
        accO = __builtin_amdgcn_mfma_f32_16x16x32_bf16(w3f[kk], hbv[kk], accO, 0, 0, 0);
    float* op = out + (size_t)(r0 + lr) * 10 + kh * 4;
    #pragma unroll
    for (int j = 0; j < 4; ++j)
        if (kh * 4 + j < 10) op[j] = accO[j];

#undef ST
#undef RD
#undef STRD
}

extern "C" void kernel_launch(void* const* d_in, const int* in_sizes, int n_in,
                              void* d_out, int out_size, void* d_ws, size_t ws_size,
                              hipStream_t stream) {
    const float* x  = (const float*)d_in[0];
    const float* W1 = (const float*)d_in[1];
    const float* b1 = (const float*)d_in[2];
    const float* W2 = (const float*)d_in[3];
    const float* b2 = (const float*)d_in[4];
    const float* W3 = (const float*)d_in[5];
    const float* b3 = (const float*)d_in[6];
    unsigned int* ws = (unsigned int*)d_ws;   // 15616 dwords = 61 KiB

    pack1<<<31, 128, 0, stream>>>(W1, b1, W2, b2, W3, b3, ws);
    pack2<<<1, 64, 0, stream>>>(ws);
    rnn_kernel<<<BTOT / 16, 64, 0, stream>>>(x, ws, (float*)d_out);
}

// Round 23
// 71.949 us; speedup vs baseline: 1.4432x; 1.0830x over previous
//
#include <hip/hip_runtime.h>

#define BTOT 65536
#define TST  28
#define PACK_DW 180
// ws layout (dwords): [0 .. 11520) packed frags (64 lanes x 180)
//                     [11520 .. 15616) WxL: 32 x 128 f32 (rows 29..31 zeroed)
#define WXL_OFF (64 * PACK_DW)

typedef __attribute__((ext_vector_type(8))) short bf16x8;
typedef __attribute__((ext_vector_type(4))) float f32x4;

__device__ __forceinline__ unsigned int f2bf(float f) {
    unsigned u = __float_as_uint(f);
    u += 0x7fff + ((u >> 16) & 1);   // RNE
    return u >> 16;
}
__device__ __forceinline__ unsigned int pk2bf(float a, float b) {
    return f2bf(a) | (f2bf(b) << 16);
}
__device__ __forceinline__ bf16x8 cvt8(f32x4 a, f32x4 b) {
    union { unsigned int u[4]; bf16x8 v; } r;
    asm("v_cvt_pk_bf16_f32 %0, %1, %2" : "=v"(r.u[0]) : "v"(a[0]), "v"(a[1]));
    asm("v_cvt_pk_bf16_f32 %0, %1, %2" : "=v"(r.u[1]) : "v"(a[2]), "v"(a[3]));
    asm("v_cvt_pk_bf16_f32 %0, %1, %2" : "=v"(r.u[2]) : "v"(b[0]), "v"(b[1]));
    asm("v_cvt_pk_bf16_f32 %0, %1, %2" : "=v"(r.u[3]) : "v"(b[2]), "v"(b[3]));
    return r.v;
}

// HIDDEN-UNIT PERMUTATION sigma (the whole trick): B-frag slot (kh,kk,jd,b)
// consumes logical unit  s = kk*32 + (jd>>1)*16 + kh*4 + (jd&1)*2 + b.
// With W2b/W3 input-rows packed by sigma, the D-layout cvt_pk dwords of acc
// tiles (2kk, 2kk+1) ARE hbv[kk] at the same lane -> the h feedback is
// register-only; the recurrence needs NO LDS round-trip at all.
// (Each kk-group permutes within its own 32-block, so every MFMA sums the
// same 32 products as before — numerics unchanged.)

// pack1: blocks 0..28 compute WxL row k (Wx = W1@W2a; row 28 = b2 + b1@W2a, hit
// by x-frag element k=28 := 1.0; block 28 zeroes rows 29..31). Block 29 packs
// W2b A-frags with sigma on the input-row index; block 30 packs W3 frags
// (sigma on rows) + b3 D-init.
// Per-lane dword layout: [0..128) w2b(kk,t8) | [128..160) wx(t8)
//                        [160..176) w3(kk)   | [176..180) b3 (f32, D rows)
__global__ void pack1(const float* __restrict__ W1, const float* __restrict__ b1,
                      const float* __restrict__ W2, const float* __restrict__ b2,
                      const float* __restrict__ W3, const float* __restrict__ b3,
                      unsigned int* __restrict__ ws) {
    float* WxL = (float*)(ws + WXL_OFF);
    const int bid = blockIdx.x, tid = threadIdx.x;
    if (bid < 29) {
        const int k = bid, n = tid;   // 128 threads
        float s = 0.f;
        if (k < 28) {
            for (int m = 0; m < 128; ++m) s += W1[k * 128 + m] * W2[m * 128 + n];
        } else {
            s = b2[n];
            for (int m = 0; m < 128; ++m) s += b1[m] * W2[m * 128 + n];
        }
        WxL[k * 128 + n] = s;
        if (k == 28) { WxL[29*128+n] = 0.f; WxL[30*128+n] = 0.f; WxL[31*128+n] = 0.f; }
    } else if (bid == 29) {
        if (tid < 64) {
            const int lr = tid & 15, kh = tid >> 4;
            unsigned int* P = ws + tid * PACK_DW;
            for (int kk = 0; kk < 4; ++kk)
                for (int t8 = 0; t8 < 8; ++t8)
                    for (int jd = 0; jd < 4; ++jd) {
                        const int s = kk * 32 + (jd >> 1) * 16 + kh * 4 + (jd & 1) * 2;
                        const int n = t8 * 16 + lr;
                        P[(kk * 8 + t8) * 4 + jd] =
                            pk2bf(W2[(128 + s) * 128 + n], W2[(129 + s) * 128 + n]);
                    }
        }
    } else {
        if (tid < 64) {
            const int lr = tid & 15, kh = tid >> 4;
            unsigned int* P = ws + tid * PACK_DW;
            for (int kk = 0; kk < 4; ++kk)
                for (int jd = 0; jd < 4; ++jd) {
                    const int s = kk * 32 + (jd >> 1) * 16 + kh * 4 + (jd & 1) * 2;
                    float lo = (lr < 10) ? W3[s * 10 + lr] : 0.f;
                    float hi = (lr < 10) ? W3[(s + 1) * 10 + lr] : 0.f;
                    P[160 + kk * 4 + jd] = pk2bf(lo, hi);
                }
            for (int j = 0; j < 4; ++j) {
                const int o = kh * 4 + j;
                P[176 + j] = __float_as_uint((o < 10) ? b3[o] : 0.f);
            }
        }
    }
}

// pack2: Wx A-frags (x's k-dimension — sigma does not apply).
__global__ void pack2(unsigned int* __restrict__ ws) {
    const int tid = threadIdx.x;
    if (tid < 64) {
        const float* WxL = (const float*)(ws + WXL_OFF);
        const int lr = tid & 15, kh = tid >> 4;
        unsigned int* P = ws + tid * PACK_DW;
        for (int t8 = 0; t8 < 8; ++t8)
            for (int jd = 0; jd < 4; ++jd) {
                const int k = kh * 8 + jd * 2, n = t8 * 16 + lr;
                P[128 + t8 * 4 + jd] = pk2bf(WxL[k * 128 + n], WxL[(k + 1) * 128 + n]);
            }
    }
}

// ZERO-LDS recurrence: 1 wave / 16 batch rows / all 128 n. h lives entirely in
// registers — sigma-packed weights make the cvt_pk outputs of acc tiles
// (2kk,2kk+1) directly equal to hbv[kk]. Per step: 40 MFMA + 32 fmax +
// 16 cvt_pk. No DS ops, no barriers; serial tail is just the cvt of the
// last-finishing acc tile (~40cy vs ~350cy for the old LDS round-trip).
__global__ __launch_bounds__(64, 2) void rnn_kernel(
    const float* __restrict__ x, const unsigned int* __restrict__ wsPack,
    float* __restrict__ out)
{
    const int lane = threadIdx.x;
    const int lr = lane & 15, kh = lane >> 4;
    const int r0 = blockIdx.x * 16;

    const unsigned int* P = wsPack + lane * PACK_DW;
    bf16x8 w2b[4][8], wx[8];
    #pragma unroll
    for (int kk = 0; kk < 4; ++kk)
        #pragma unroll
        for (int t8 = 0; t8 < 8; ++t8)
            w2b[kk][t8] = *(const bf16x8*)(P + (kk * 8 + t8) * 4);
    #pragma unroll
    for (int t8 = 0; t8 < 8; ++t8) wx[t8] = *(const bf16x8*)(P + 128 + t8 * 4);

    // x B-frag: lane (kh,lr) covers k = 8kh + j of x[r0+lr][28t + k];
    // kh==3 upper half = {1.0 (k=28 bias hook), 0, 0, 0} — Wx rows 29..31 zero.
    const f32x4 onec = {1.f, 0.f, 0.f, 0.f};
    const float* xr = x + (size_t)(r0 + lr) * 784 + 8 * kh;
    f32x4 xa = *(const f32x4*)xr;
    f32x4 xc = (kh < 3) ? *(const f32x4*)(xr + 4) : onec;
    bf16x8 xb = cvt8(xa, xc);
    const f32x4 z4 = {0.f, 0.f, 0.f, 0.f};

    f32x4 acc[8];
    union HF { unsigned int u[4]; bf16x8 v; } hb[4];
    f32x4 na, nc;

// relu + pack acc[T8] -> the two dwords of hb[T8>>1] at offset (T8&1)*2.
// All indices compile-time -> stays in registers (SROA).
#define CVT(T8) do {                                                        \
        f32x4 v = acc[T8];                                                  \
        v[0] = fmaxf(v[0], 0.f); v[1] = fmaxf(v[1], 0.f);                   \
        v[2] = fmaxf(v[2], 0.f); v[3] = fmaxf(v[3], 0.f);                   \
        unsigned lo, hi;                                                    \
        asm("v_cvt_pk_bf16_f32 %0, %1, %2" : "=v"(lo) : "v"(v[0]), "v"(v[1])); \
        asm("v_cvt_pk_bf16_f32 %0, %1, %2" : "=v"(hi) : "v"(v[2]), "v"(v[3])); \
        hb[(T8) >> 1].u[((T8) & 1) * 2]     = lo;                           \
        hb[(T8) >> 1].u[((T8) & 1) * 2 + 1] = hi;                           \
    } while (0)
#define CVTALL  CVT(0); CVT(1); CVT(2); CVT(3); CVT(4); CVT(5); CVT(6); CVT(7)

    // ---- step 0: h0 == 0, so only the x part (exact) ----
    {
        const float* xp = xr + 28;
        na = *(const f32x4*)xp;
        nc = (kh < 3) ? *(const f32x4*)(xp + 4) : onec;
        __builtin_amdgcn_s_setprio(1);
        #pragma unroll
        for (int t8 = 0; t8 < 8; ++t8)
            acc[t8] = __builtin_amdgcn_mfma_f32_16x16x32_bf16(wx[t8], xb, z4, 0, 0, 0);
        __builtin_amdgcn_s_setprio(0);
        xb = cvt8(na, nc);
        CVTALL;
    }

    // ---- steps 1..27 ----
    #pragma unroll 2
    for (int t = 1; t < TST; ++t) {
        const bool pf = (t + 1 < TST);
        if (pf) {
            const float* xp = xr + (t + 1) * 28;
            na = *(const f32x4*)xp;
            nc = (kh < 3) ? *(const f32x4*)(xp + 4) : onec;
        }
        __builtin_amdgcn_s_setprio(1);
        #pragma unroll
        for (int t8 = 0; t8 < 8; ++t8)
            acc[t8] = __builtin_amdgcn_mfma_f32_16x16x32_bf16(wx[t8], xb, z4, 0, 0, 0);
        #pragma unroll
        for (int kk = 0; kk < 4; ++kk)
            #pragma unroll
            for (int t8 = 0; t8 < 8; ++t8)
                acc[t8] = __builtin_amdgcn_mfma_f32_16x16x32_bf16(w2b[kk][t8], hb[kk].v, acc[t8], 0, 0, 0);
        __builtin_amdgcn_s_setprio(0);
        if (pf) xb = cvt8(na, nc);
        CVTALL;   // registers ARE next step's B-frags (sigma packing)
    }

    // epilogue: out^T = W3^T . h_final^T + b3 — hb holds h_final already
    bf16x8 w3f[4];
    #pragma unroll
    for (int kk = 0; kk < 4; ++kk) w3f[kk] = *(const bf16x8*)(P + 160 + kk * 4);
    const float* bp = (const float*)(P + 176);
    f32x4 accO = {bp[0], bp[1], bp[2], bp[3]};
    #pragma unroll
    for (int kk = 0; kk < 4; ++kk)
        accO = __builtin_amdgcn_mfma_f32_16x16x32_bf16(w3f[kk], hb[kk].v, accO, 0, 0, 0);
    float* op = out + (size_t)(r0 + lr) * 10 + kh * 4;
    #pragma unroll
    for (int j = 0; j < 4; ++j)
        if (kh * 4 + j < 10) op[j] = accO[j];

#undef CVT
#undef CVTALL
}

extern "C" void kernel_launch(void* const* d_in, const int* in_sizes, int n_in,
                              void* d_out, int out_size, void* d_ws, size_t ws_size,
                              hipStream_t stream) {
    const float* x  = (const float*)d_in[0];
    const float* W1 = (const float*)d_in[1];
    const float* b1 = (const float*)d_in[2];
    const float* W2 = (const float*)d_in[3];
    const float* b2 = (const float*)d_in[4];
    const float* W3 = (const float*)d_in[5];
    const float* b3 = (const float*)d_in[6];
    unsigned int* ws = (unsigned int*)d_ws;   // 15616 dwords = 61 KiB

    pack1<<<31, 128, 0, stream>>>(W1, b1, W2, b2, W3, b3, ws);
    pack2<<<1, 64, 0, stream>>>(ws);
    rnn_kernel<<<BTOT / 16, 64, 0, stream>>>(x, ws, (float*)d_out);
}